// Round 5
// baseline (310.924 us; speedup 1.0000x reference)
//
#include <hip/hip_runtime.h>

#define HID 32
#define MAXDEG 32   // in-degree ~Binomial(1e5, 1/25e3), mean 4; P(deg>32) ~ 0

// ---- build ELL adjacency: deg[v] = in-degree, ell[v*MAXDEG + slot] = edge id ----
__global__ __launch_bounds__(256) void build_ell_kernel(
    const int* __restrict__ dst, int* __restrict__ deg, int* __restrict__ ell, int E)
{
    int e = blockIdx.x * blockDim.x + threadIdx.x;
    if (e >= E) return;
    int d = dst[e];
    int slot = atomicAdd(deg + d, 1);
    if (slot < MAXDEG) ell[d * MAXDEG + slot] = e;
}

// ---- fused NNConv layer: one wave64 per 8 nodes, half-waves split the i-range ----
// lane = o | (ihalf<<5). Edge-MLP weight column lives in VGPRs (4*IH+IH = 80 dwords).
// Edge ids + src ids are lane-resident for the whole node (1 ELL-row load + 1 gather);
// per-edge broadcast via __shfl. Ping-pong prefetch of (ea, x-row), no register rotates.
// NO LDS, NO fp32 atomics.
template<int IN, bool FUSE_HEAD>
__global__ __launch_bounds__(256, 3) void conv_kernel(
    const float* __restrict__ x_in,            // [N, IN]
    const int* __restrict__ src,               // [E]
    const float* __restrict__ ea,              // [E, 4]
    const int* __restrict__ deg,               // [N]
    const int* __restrict__ ell,               // [N, MAXDEG]
    const float* __restrict__ w_mlp,           // [4, IN*HID]
    const float* __restrict__ b_mlp,           // [IN*HID]
    const float* __restrict__ root,            // [IN, HID]
    const float* __restrict__ bias,            // [HID]
    const float* __restrict__ hw1, const float* __restrict__ hb1,  // head
    const float* __restrict__ hw2, const float* __restrict__ hb2,
    float* __restrict__ out,                   // [N,HID] or [N,1] if FUSE_HEAD
    int N)
{
    constexpr int IH = IN / 2;                 // i's per half-wave
    constexpr int NC = IH / 4;                 // float4 chunks per half
    constexpr int NPW = 8;                     // nodes per wave (preload amortization)

    const int lane = threadIdx.x & 63;
    const int o    = lane & 31;                // output channel
    const int i0   = (lane >> 5) * IH;         // my half's first input channel

    // per-lane edge-MLP weight column + bias column (persist across this wave's nodes)
    float w[4][IH], bm[IH];
    #pragma unroll
    for (int k = 0; k < 4; ++k)
        #pragma unroll
        for (int i = 0; i < IH; ++i)
            w[k][i] = w_mlp[(k * IN + i0 + i) * HID + o];   // coalesced across o
    #pragma unroll
    for (int i = 0; i < IH; ++i)
        bm[i] = b_mlp[(i0 + i) * HID + o];
    const float bo = bias[o];

    const int wav = (blockIdx.x * blockDim.x + threadIdx.x) >> 6;
    const int v0 = wav * NPW;
    const int v1 = (v0 + NPW < N) ? v0 + NPW : N;

    for (int v = v0; v < v1; ++v) {
        const int dv  = deg[v];
        const int dvc = dv < MAXDEG ? dv : MAXDEG;

        // all edge ids for this node, one per lane (halves duplicate)
        int e_l = ell[v * MAXDEG + (lane & 31)];
        if ((lane & 31) >= dvc) e_l = 0;       // clamp poison slots to a valid id
        int s_l = src[e_l];                    // src node per lane

        float acc = 0.f;
        float4 aA, aB, xA[NC], xB[NC];

        auto loadE = [&](int j, float4& a, float4* xq) {
            int ej = __shfl(e_l, j, 32);
            int sj = __shfl(s_l, j, 32);
            a = *(const float4*)(ea + (size_t)ej * 4);
            #pragma unroll
            for (int c = 0; c < NC; ++c)
                xq[c] = *(const float4*)(x_in + (size_t)sj * IN + i0 + c * 4);
        };
        auto comp = [&](const float4& a, const float4* xq) {
            #pragma unroll
            for (int c = 0; c < NC; ++c) {
                const float* x4 = (const float*)&xq[c];
                #pragma unroll
                for (int u = 0; u < 4; ++u) {
                    const int i = c * 4 + u;
                    float t = fmaf(a.x, w[0][i], bm[i]);
                    t = fmaf(a.y, w[1][i], t);
                    t = fmaf(a.z, w[2][i], t);
                    t = fmaf(a.w, w[3][i], t);
                    t = fmaxf(t, 0.f);                 // relu(edge-MLP)
                    acc = fmaf(x4[u], t, acc);
                }
            }
        };

        if (dvc > 0) {
            loadE(0, aA, xA);
            int j = 0;
            while (true) {
                if (j + 1 < dvc) loadE(j + 1, aB, xB);   // prefetch next into B
                comp(aA, xA);
                if (++j >= dvc) break;
                if (j + 1 < dvc) loadE(j + 1, aA, xA);   // prefetch next into A
                comp(aB, xB);
                if (++j >= dvc) break;
            }
        }

        // epilogue: merge halves, root transform (loads off the loop's register peak)
        float accT = acc + __shfl_xor(acc, 32);
        float r = 0.f;
        #pragma unroll
        for (int c = 0; c < NC; ++c) {
            float4 xv = *(const float4*)(x_in + (size_t)v * IN + i0 + c * 4);
            const float* xv4 = (const float*)&xv;
            #pragma unroll
            for (int u = 0; u < 4; ++u)
                r = fmaf(xv4[u], root[(i0 + c * 4 + u) * HID + o], r);
        }
        float rT = r + __shfl_xor(r, 32);
        float m = accT / fmaxf((float)dv, 1.0f);
        float h = fmaxf(m + rT + bo, 0.f);     // identical in both halves

        if (!FUSE_HEAD) {
            if (lane < 32) out[(size_t)v * HID + o] = h;
        } else {
            float t = hb1[o];
            #pragma unroll
            for (int i = 0; i < HID; ++i)
                t = fmaf(__shfl(h, i, 32), hw1[i * HID + o], t);
            t = fmaxf(t, 0.f) * hw2[o];
            #pragma unroll
            for (int dd = 16; dd > 0; dd >>= 1)
                t += __shfl_down(t, dd, 32);
            if (lane == 0) out[v] = t + hb2[0];
        }
    }
}

extern "C" void kernel_launch(void* const* d_in, const int* in_sizes, int n_in,
                              void* d_out, int out_size, void* d_ws, size_t ws_size,
                              hipStream_t stream)
{
    const float* x      = (const float*)d_in[0];
    const int*   ei     = (const int*)d_in[1];     // [2, E]
    const float* ea     = (const float*)d_in[2];
    const float* w_mlp1 = (const float*)d_in[3];
    const float* b_mlp1 = (const float*)d_in[4];
    const float* root1  = (const float*)d_in[5];
    const float* bias1  = (const float*)d_in[6];
    const float* w_mlp2 = (const float*)d_in[7];
    const float* b_mlp2 = (const float*)d_in[8];
    const float* root2  = (const float*)d_in[9];
    const float* bias2  = (const float*)d_in[10];
    const float* w_mlp3 = (const float*)d_in[11];
    const float* b_mlp3 = (const float*)d_in[12];
    const float* root3  = (const float*)d_in[13];
    const float* bias3  = (const float*)d_in[14];
    const float* w_out1 = (const float*)d_in[15];
    const float* b_out1 = (const float*)d_in[16];
    const float* w_out2 = (const float*)d_in[17];
    const float* b_out2 = (const float*)d_in[18];

    const int NODE_IN = 8;
    const int N = in_sizes[0] / NODE_IN;            // 25000
    const int E = in_sizes[2] / 4;                  // 100000
    const int* src = ei;
    const int* dst = ei + E;

    char* ws = (char*)d_ws;
    size_t off = 0;
    auto carve = [&](size_t bytes) {
        char* p = ws + off;
        off += (bytes + 255) & ~(size_t)255;
        return p;
    };
    int*   deg = (int*)carve((size_t)N * 4);
    int*   ell = (int*)carve((size_t)N * MAXDEG * 4);
    float* h1  = (float*)carve((size_t)N * HID * 4);
    float* h2  = (float*)carve((size_t)N * HID * 4);
    float* outp = (float*)d_out;

    const int TB = 256;
    const int edgeBlocks = (E + TB - 1) / TB;                   // 391
    const int NPW = 8;
    const int nwaves = (N + NPW - 1) / NPW;                     // 3125
    const int convBlocks = (nwaves * 64 + TB - 1) / TB;         // 782

    // 1) zero degree counters
    hipMemsetAsync(deg, 0, (size_t)N * 4, stream);
    // 2) build ELL adjacency (int atomics only)
    build_ell_kernel<<<edgeBlocks, TB, 0, stream>>>(dst, deg, ell, E);
    // 3) conv1 (IN=8)
    conv_kernel<8, false><<<convBlocks, TB, 0, stream>>>(
        x, src, ea, deg, ell, w_mlp1, b_mlp1, root1, bias1,
        nullptr, nullptr, nullptr, nullptr, h1, N);
    // 4) conv2 (IN=32)
    conv_kernel<32, false><<<convBlocks, TB, 0, stream>>>(
        h1, src, ea, deg, ell, w_mlp2, b_mlp2, root2, bias2,
        nullptr, nullptr, nullptr, nullptr, h2, N);
    // 5) conv3 (IN=32) + fused output head
    conv_kernel<32, true><<<convBlocks, TB, 0, stream>>>(
        h2, src, ea, deg, ell, w_mlp3, b_mlp3, root3, bias3,
        w_out1, b_out1, w_out2, b_out2, outp, N);
}

// Round 6
// 271.633 us; speedup vs baseline: 1.1447x; 1.1447x over previous
//
#include <hip/hip_runtime.h>

#define HID 32
#define MAXDEG 32   // in-degree ~Binomial(1e5, 1/25e3), mean 4; P(deg>32) ~ 0
#define EPW 16      // edges per wave in msg_kernel

// ---- build ELL adjacency: deg[v] = in-degree, ell[v*MAXDEG + slot] = edge id ----
__global__ __launch_bounds__(256) void build_ell_kernel(
    const int* __restrict__ dst, int* __restrict__ deg, int* __restrict__ ell, int E)
{
    int e = blockIdx.x * blockDim.x + threadIdx.x;
    if (e >= E) return;
    int d = dst[e];
    int slot = atomicAdd(deg + d, 1);
    if (slot < MAXDEG) ell[d * MAXDEG + slot] = e;
}

// ---- phase 1: per-edge message, NO atomics, NO LDS ----
// wave64 = 1 edge; lane = o | (ihalf<<5). Per-lane edge-MLP weight column:
// 4*IH + IH = 80 dwords (IN=32) held in VGPRs. Edges are sequential per wave
// (streaming ea/src); x[src] row is the only gather, covered by 1-iter src prefetch.
// msg[e][o] = sum_i x[src[e]][i] * relu(ea[e]@W + b)[i][o]
template<int IN>
__global__ __launch_bounds__(256, 3) void msg_kernel(
    const float* __restrict__ x_in,            // [N, IN]
    const int* __restrict__ src,               // [E]
    const float* __restrict__ ea,              // [E, 4]
    const float* __restrict__ w_mlp,           // [4, IN*HID]
    const float* __restrict__ b_mlp,           // [IN*HID]
    float* __restrict__ msg,                   // [E, HID]
    int E)
{
    constexpr int IH = IN / 2;                 // i's per half-wave
    constexpr int NC = IH / 4;                 // float4 chunks per half

    const int lane = threadIdx.x & 63;
    const int o    = lane & 31;                // output channel
    const int i0   = (lane >> 5) * IH;         // my half's first input channel

    // per-lane weight column (coalesced across o), persists across EPW edges
    float w0[IH], w1[IH], w2[IH], w3[IH], bm[IH];
    #pragma unroll
    for (int i = 0; i < IH; ++i) {
        w0[i] = w_mlp[(0 * IN + i0 + i) * HID + o];
        w1[i] = w_mlp[(1 * IN + i0 + i) * HID + o];
        w2[i] = w_mlp[(2 * IN + i0 + i) * HID + o];
        w3[i] = w_mlp[(3 * IN + i0 + i) * HID + o];
        bm[i] = b_mlp[(i0 + i) * HID + o];
    }

    const int wav = (blockIdx.x * blockDim.x + threadIdx.x) >> 6;
    const int e0 = wav * EPW;
    const int e1 = (e0 + EPW < E) ? e0 + EPW : E;
    if (e0 >= E) return;

    int s = src[e0];                           // prefetched src id
    for (int e = e0; e < e1; ++e) {
        int s_next = (e + 1 < e1) ? src[e + 1] : 0;     // next iter's gather target
        float4 a = *(const float4*)(ea + (size_t)e * 4);

        float4 xq[NC];
        #pragma unroll
        for (int c = 0; c < NC; ++c)
            xq[c] = *(const float4*)(x_in + (size_t)s * IN + i0 + c * 4);

        float acc = 0.f;
        #pragma unroll
        for (int c = 0; c < NC; ++c) {
            const float* x4 = (const float*)&xq[c];
            #pragma unroll
            for (int u = 0; u < 4; ++u) {
                const int i = c * 4 + u;
                float t = fmaf(a.x, w0[i], bm[i]);
                t = fmaf(a.y, w1[i], t);
                t = fmaf(a.z, w2[i], t);
                t = fmaf(a.w, w3[i], t);
                t = fmaxf(t, 0.f);             // relu(edge-MLP)
                acc = fmaf(x4[u], t, acc);
            }
        }
        acc += __shfl_xor(acc, 32);            // merge i-halves
        if (lane < 32) msg[(size_t)e * HID + o] = acc;
        s = s_next;
    }
}

// ---- phase 2: gather msg rows via ELL, node update (+ optional fused head) ----
// 32 lanes per node; lane = o. msg row reads are fully coalesced (128 B).
template<int IN, bool FUSE_HEAD>
__global__ __launch_bounds__(256) void agg_kernel(
    const float* __restrict__ x_in,            // [N, IN] (layer input, for root)
    const float* __restrict__ msg,             // [E, HID]
    const int* __restrict__ deg,               // [N]
    const int* __restrict__ ell,               // [N, MAXDEG]
    const float* __restrict__ root,            // [IN, HID]
    const float* __restrict__ bias,            // [HID]
    const float* __restrict__ hw1, const float* __restrict__ hb1,
    const float* __restrict__ hw2, const float* __restrict__ hb2,
    float* __restrict__ out,                   // [N,HID] or [N,1] if FUSE_HEAD
    int N)
{
    int idx = blockIdx.x * blockDim.x + threadIdx.x;
    int v = idx >> 5, o = idx & 31;
    if (v >= N) return;

    const int dv  = deg[v];
    const int dvc = dv < MAXDEG ? dv : MAXDEG;
    const int* el = ell + v * MAXDEG;

    float acc = 0.f;
    for (int j = 0; j < dvc; ++j)
        acc += msg[(size_t)el[j] * HID + o];

    float r = bias[o];
    const float* xv = x_in + (size_t)v * IN;
    #pragma unroll
    for (int i = 0; i < IN; ++i)
        r = fmaf(xv[i], root[i * HID + o], r);

    float m = acc / fmaxf((float)dv, 1.0f);
    float h = fmaxf(m + r, 0.f);

    if (!FUSE_HEAD) {
        out[(size_t)v * HID + o] = h;
    } else {
        float t = hb1[o];
        #pragma unroll
        for (int i = 0; i < HID; ++i)
            t = fmaf(__shfl(h, i, 32), hw1[i * HID + o], t);
        t = fmaxf(t, 0.f) * hw2[o];
        #pragma unroll
        for (int dd = 16; dd > 0; dd >>= 1)
            t += __shfl_down(t, dd, 32);
        if (o == 0) out[v] = t + hb2[0];
    }
}

extern "C" void kernel_launch(void* const* d_in, const int* in_sizes, int n_in,
                              void* d_out, int out_size, void* d_ws, size_t ws_size,
                              hipStream_t stream)
{
    const float* x      = (const float*)d_in[0];
    const int*   ei     = (const int*)d_in[1];     // [2, E]
    const float* ea     = (const float*)d_in[2];
    const float* w_mlp1 = (const float*)d_in[3];
    const float* b_mlp1 = (const float*)d_in[4];
    const float* root1  = (const float*)d_in[5];
    const float* bias1  = (const float*)d_in[6];
    const float* w_mlp2 = (const float*)d_in[7];
    const float* b_mlp2 = (const float*)d_in[8];
    const float* root2  = (const float*)d_in[9];
    const float* bias2  = (const float*)d_in[10];
    const float* w_mlp3 = (const float*)d_in[11];
    const float* b_mlp3 = (const float*)d_in[12];
    const float* root3  = (const float*)d_in[13];
    const float* bias3  = (const float*)d_in[14];
    const float* w_out1 = (const float*)d_in[15];
    const float* b_out1 = (const float*)d_in[16];
    const float* w_out2 = (const float*)d_in[17];
    const float* b_out2 = (const float*)d_in[18];

    const int NODE_IN = 8;
    const int N = in_sizes[0] / NODE_IN;            // 25000
    const int E = in_sizes[2] / 4;                  // 100000
    const int* src = ei;
    const int* dst = ei + E;

    char* ws = (char*)d_ws;
    size_t off = 0;
    auto carve = [&](size_t bytes) {
        char* p = ws + off;
        off += (bytes + 255) & ~(size_t)255;
        return p;
    };
    int*   deg = (int*)carve((size_t)N * 4);
    int*   ell = (int*)carve((size_t)N * MAXDEG * 4);
    float* h1  = (float*)carve((size_t)N * HID * 4);
    float* h2  = (float*)carve((size_t)N * HID * 4);
    float* msg = (float*)carve((size_t)E * HID * 4);
    float* outp = (float*)d_out;

    const int TB = 256;
    const int edgeBlocks = (E + TB - 1) / TB;                   // 391
    const int nwavesMsg  = (E + EPW - 1) / EPW;                 // 6250
    const int msgBlocks  = (nwavesMsg * 64 + TB - 1) / TB;      // 1563
    const int aggBlocks  = (N * HID + TB - 1) / TB;             // 3125

    // 1) zero degree counters
    hipMemsetAsync(deg, 0, (size_t)N * 4, stream);
    // 2) build ELL adjacency (int atomics only)
    build_ell_kernel<<<edgeBlocks, TB, 0, stream>>>(dst, deg, ell, E);

    // conv1 (IN=8)
    msg_kernel<8><<<msgBlocks, TB, 0, stream>>>(x, src, ea, w_mlp1, b_mlp1, msg, E);
    agg_kernel<8, false><<<aggBlocks, TB, 0, stream>>>(
        x, msg, deg, ell, root1, bias1, nullptr, nullptr, nullptr, nullptr, h1, N);

    // conv2 (IN=32)
    msg_kernel<32><<<msgBlocks, TB, 0, stream>>>(h1, src, ea, w_mlp2, b_mlp2, msg, E);
    agg_kernel<32, false><<<aggBlocks, TB, 0, stream>>>(
        h1, msg, deg, ell, root2, bias2, nullptr, nullptr, nullptr, nullptr, h2, N);

    // conv3 (IN=32) + fused output head
    msg_kernel<32><<<msgBlocks, TB, 0, stream>>>(h2, src, ea, w_mlp3, b_mlp3, msg, E);
    agg_kernel<32, true><<<aggBlocks, TB, 0, stream>>>(
        h2, msg, deg, ell, root3, bias3, w_out1, b_out1, w_out2, b_out2, outp, N);
}

// Round 7
// 270.807 us; speedup vs baseline: 1.1481x; 1.0030x over previous
//
#include <hip/hip_runtime.h>

#define HID 32
#define MAXDEG 32   // in-degree ~Binomial(1e5, 1/25e3), mean 4; P(deg>32) ~ 0
#define EPW 16      // edges per wave in msg_kernel

// ---- build ELL adjacency: deg[v] = in-degree, ell[v*MAXDEG + slot] = edge id ----
__global__ __launch_bounds__(256) void build_ell_kernel(
    const int* __restrict__ dst, int* __restrict__ deg, int* __restrict__ ell, int E)
{
    int e = blockIdx.x * blockDim.x + threadIdx.x;
    if (e >= E) return;
    int d = dst[e];
    int slot = atomicAdd(deg + d, 1);
    if (slot < MAXDEG) ell[d * MAXDEG + slot] = e;
}

// ---- phase 1: per-edge message, NO atomics, NO LDS ----
// wave64 = 1 edge; lane = o | (ihalf<<5). Per-lane edge-MLP weight column:
// 4*IH + IH = 80 dwords (IN=32) held in VGPRs — PINNED via empty asm so the
// backend cannot sink/remat the invariant loads back into the loop (R6: VGPR=56,
// weights were re-loaded per edge -> latency-bound at 29% VALUBusy).
// msg[e][o] = sum_i x[src[e]][i] * relu(ea[e]@W + b)[i][o]
template<int IN>
__global__ __launch_bounds__(256, 3) void msg_kernel(
    const float* __restrict__ x_in,            // [N, IN]
    const int* __restrict__ src,               // [E]
    const float* __restrict__ ea,              // [E, 4]
    const float* __restrict__ w_mlp,           // [4, IN*HID]
    const float* __restrict__ b_mlp,           // [IN*HID]
    float* __restrict__ msg,                   // [E, HID]
    int E)
{
    constexpr int IH = IN / 2;                 // i's per half-wave
    constexpr int NC = IH / 4;                 // float4 chunks per half

    const int lane = threadIdx.x & 63;
    const int o    = lane & 31;                // output channel
    const int i0   = (lane >> 5) * IH;         // my half's first input channel

    // per-lane weight column (coalesced across o), persists across EPW edges
    float w0[IH], w1[IH], w2[IH], w3[IH], bm[IH];
    #pragma unroll
    for (int i = 0; i < IH; ++i) {
        w0[i] = w_mlp[(0 * IN + i0 + i) * HID + o];
        w1[i] = w_mlp[(1 * IN + i0 + i) * HID + o];
        w2[i] = w_mlp[(2 * IN + i0 + i) * HID + o];
        w3[i] = w_mlp[(3 * IN + i0 + i) * HID + o];
        bm[i] = b_mlp[(i0 + i) * HID + o];
    }
    // pin: make values opaque so they MUST stay in VGPRs (blocks load sinking)
    #pragma unroll
    for (int i = 0; i < IH; ++i)
        asm volatile("" : "+v"(w0[i]), "+v"(w1[i]), "+v"(w2[i]), "+v"(w3[i]), "+v"(bm[i]));

    const int wav = (blockIdx.x * blockDim.x + threadIdx.x) >> 6;
    const int e0 = wav * EPW;
    const int e1 = (e0 + EPW < E) ? e0 + EPW : E;
    if (e0 >= E) return;

    int s = src[e0];                           // prefetched src id
    for (int e = e0; e < e1; ++e) {
        int s_next = (e + 1 < e1) ? src[e + 1] : 0;     // next iter's gather target
        float4 a = *(const float4*)(ea + (size_t)e * 4);

        float4 xq[NC];
        #pragma unroll
        for (int c = 0; c < NC; ++c)
            xq[c] = *(const float4*)(x_in + (size_t)s * IN + i0 + c * 4);

        float acc = 0.f;
        #pragma unroll
        for (int c = 0; c < NC; ++c) {
            const float* x4 = (const float*)&xq[c];
            #pragma unroll
            for (int u = 0; u < 4; ++u) {
                const int i = c * 4 + u;
                float t = fmaf(a.x, w0[i], bm[i]);
                t = fmaf(a.y, w1[i], t);
                t = fmaf(a.z, w2[i], t);
                t = fmaf(a.w, w3[i], t);
                t = fmaxf(t, 0.f);             // relu(edge-MLP)
                acc = fmaf(x4[u], t, acc);
            }
        }
        acc += __shfl_xor(acc, 32);            // merge i-halves
        if (lane < 32) msg[(size_t)e * HID + o] = acc;
        s = s_next;
    }
}

// ---- phase 2: gather msg rows via ELL, node update (+ optional fused head) ----
// 32 lanes per node; lane = o. msg row reads are fully coalesced (128 B).
template<int IN, bool FUSE_HEAD>
__global__ __launch_bounds__(256) void agg_kernel(
    const float* __restrict__ x_in,            // [N, IN] (layer input, for root)
    const float* __restrict__ msg,             // [E, HID]
    const int* __restrict__ deg,               // [N]
    const int* __restrict__ ell,               // [N, MAXDEG]
    const float* __restrict__ root,            // [IN, HID]
    const float* __restrict__ bias,            // [HID]
    const float* __restrict__ hw1, const float* __restrict__ hb1,
    const float* __restrict__ hw2, const float* __restrict__ hb2,
    float* __restrict__ out,                   // [N,HID] or [N,1] if FUSE_HEAD
    int N)
{
    int idx = blockIdx.x * blockDim.x + threadIdx.x;
    int v = idx >> 5, o = idx & 31;
    if (v >= N) return;

    const int dv  = deg[v];
    const int dvc = dv < MAXDEG ? dv : MAXDEG;
    const int* el = ell + v * MAXDEG;

    float acc = 0.f;
    for (int j = 0; j < dvc; ++j)
        acc += msg[(size_t)el[j] * HID + o];

    float r = bias[o];
    const float* xv = x_in + (size_t)v * IN;
    #pragma unroll
    for (int i = 0; i < IN; ++i)
        r = fmaf(xv[i], root[i * HID + o], r);

    float m = acc / fmaxf((float)dv, 1.0f);
    float h = fmaxf(m + r, 0.f);

    if (!FUSE_HEAD) {
        out[(size_t)v * HID + o] = h;
    } else {
        float t = hb1[o];
        #pragma unroll
        for (int i = 0; i < HID; ++i)
            t = fmaf(__shfl(h, i, 32), hw1[i * HID + o], t);
        t = fmaxf(t, 0.f) * hw2[o];
        #pragma unroll
        for (int dd = 16; dd > 0; dd >>= 1)
            t += __shfl_down(t, dd, 32);
        if (o == 0) out[v] = t + hb2[0];
    }
}

extern "C" void kernel_launch(void* const* d_in, const int* in_sizes, int n_in,
                              void* d_out, int out_size, void* d_ws, size_t ws_size,
                              hipStream_t stream)
{
    const float* x      = (const float*)d_in[0];
    const int*   ei     = (const int*)d_in[1];     // [2, E]
    const float* ea     = (const float*)d_in[2];
    const float* w_mlp1 = (const float*)d_in[3];
    const float* b_mlp1 = (const float*)d_in[4];
    const float* root1  = (const float*)d_in[5];
    const float* bias1  = (const float*)d_in[6];
    const float* w_mlp2 = (const float*)d_in[7];
    const float* b_mlp2 = (const float*)d_in[8];
    const float* root2  = (const float*)d_in[9];
    const float* bias2  = (const float*)d_in[10];
    const float* w_mlp3 = (const float*)d_in[11];
    const float* b_mlp3 = (const float*)d_in[12];
    const float* root3  = (const float*)d_in[13];
    const float* bias3  = (const float*)d_in[14];
    const float* w_out1 = (const float*)d_in[15];
    const float* b_out1 = (const float*)d_in[16];
    const float* w_out2 = (const float*)d_in[17];
    const float* b_out2 = (const float*)d_in[18];

    const int NODE_IN = 8;
    const int N = in_sizes[0] / NODE_IN;            // 25000
    const int E = in_sizes[2] / 4;                  // 100000
    const int* src = ei;
    const int* dst = ei + E;

    char* ws = (char*)d_ws;
    size_t off = 0;
    auto carve = [&](size_t bytes) {
        char* p = ws + off;
        off += (bytes + 255) & ~(size_t)255;
        return p;
    };
    int*   deg = (int*)carve((size_t)N * 4);
    int*   ell = (int*)carve((size_t)N * MAXDEG * 4);
    float* h1  = (float*)carve((size_t)N * HID * 4);
    float* h2  = (float*)carve((size_t)N * HID * 4);
    float* msg = (float*)carve((size_t)E * HID * 4);
    float* outp = (float*)d_out;

    const int TB = 256;
    const int edgeBlocks = (E + TB - 1) / TB;                   // 391
    const int nwavesMsg  = (E + EPW - 1) / EPW;                 // 6250
    const int msgBlocks  = (nwavesMsg * 64 + TB - 1) / TB;      // 1563
    const int aggBlocks  = (N * HID + TB - 1) / TB;             // 3125

    // 1) zero degree counters
    hipMemsetAsync(deg, 0, (size_t)N * 4, stream);
    // 2) build ELL adjacency (int atomics only)
    build_ell_kernel<<<edgeBlocks, TB, 0, stream>>>(dst, deg, ell, E);

    // conv1 (IN=8)
    msg_kernel<8><<<msgBlocks, TB, 0, stream>>>(x, src, ea, w_mlp1, b_mlp1, msg, E);
    agg_kernel<8, false><<<aggBlocks, TB, 0, stream>>>(
        x, msg, deg, ell, root1, bias1, nullptr, nullptr, nullptr, nullptr, h1, N);

    // conv2 (IN=32)
    msg_kernel<32><<<msgBlocks, TB, 0, stream>>>(h1, src, ea, w_mlp2, b_mlp2, msg, E);
    agg_kernel<32, false><<<aggBlocks, TB, 0, stream>>>(
        h1, msg, deg, ell, root2, bias2, nullptr, nullptr, nullptr, nullptr, h2, N);

    // conv3 (IN=32) + fused output head
    msg_kernel<32><<<msgBlocks, TB, 0, stream>>>(h2, src, ea, w_mlp3, b_mlp3, msg, E);
    agg_kernel<32, true><<<aggBlocks, TB, 0, stream>>>(
        h2, msg, deg, ell, root3, bias3, w_out1, b_out1, w_out2, b_out2, outp, N);
}